// Round 7
// baseline (490.910 us; speedup 1.0000x reference)
//
#include <hip/hip_runtime.h>

#define NF 128
#define NGRAPHS 64
#define NCLS 10
#define NPARTS 256         // dst partitions, 512 nodes each (n <= 131072)
#define PART_SHIFT 9
#define PART_NODES 512
#define PART_CAP 9216      // mean 6250 + ~37 sigma slack
#define SPLIT_TILE 4096
#define AS_STRIDE 136      // bf16 elems per LDS A-row (128 + 8 pad)
#define SRC_BITS 17        // src < 2^17 (n <= 131072); record = dlocal<<17 | src

typedef __attribute__((ext_vector_type(8))) short bf16x8;          // MFMA frag
typedef __attribute__((ext_vector_type(4))) float f32x4;
typedef __attribute__((ext_vector_type(8))) unsigned short u16x8;  // 16B row chunk

__device__ __forceinline__ float bf2f(unsigned short u) {
    union { unsigned int i; float f; } v; v.i = ((unsigned int)u) << 16; return v.f;
}
__device__ __forceinline__ unsigned short f2bf(float f) {
    union { float f; unsigned int i; } v; v.f = f;
    unsigned int lsb = (v.i >> 16) & 1;
    v.i += 0x7fffu + lsb;                 // RNE
    return (unsigned short)(v.i >> 16);
}

// ---------------------------------------------------------------------------
// Register-path per-node gather (round-1 form, best measured: 76 us/layer =
// 5.4 TB/s delivered = 86% of streaming ceiling; invariant to MLP depth /
// L2 residency / LDS-DMA — r0/r2/r3 A/B. Requires >~40% occupancy to
// saturate (r6: 19.6% occ -> 134 us). Do not restructure.
// ---------------------------------------------------------------------------
__device__ __forceinline__ void gather_node(
    const unsigned short* __restrict__ x, const int* __restrict__ offs,
    const int* __restrict__ eid, int node, int n, int c, float acc[8]) {
#pragma unroll
    for (int r = 0; r < 8; ++r) acc[r] = 0.f;
    if (node >= n) return;
    int j = offs[node];
    int end = offs[node + 1];
    for (; j + 8 <= end; j += 8) {
        int s0 = eid[j + 0], s1 = eid[j + 1], s2 = eid[j + 2], s3 = eid[j + 3];
        int s4 = eid[j + 4], s5 = eid[j + 5], s6 = eid[j + 6], s7 = eid[j + 7];
        u16x8 v0 = ((const u16x8*)(x + (size_t)s0 * NF))[c];
        u16x8 v1 = ((const u16x8*)(x + (size_t)s1 * NF))[c];
        u16x8 v2 = ((const u16x8*)(x + (size_t)s2 * NF))[c];
        u16x8 v3 = ((const u16x8*)(x + (size_t)s3 * NF))[c];
        u16x8 v4 = ((const u16x8*)(x + (size_t)s4 * NF))[c];
        u16x8 v5 = ((const u16x8*)(x + (size_t)s5 * NF))[c];
        u16x8 v6 = ((const u16x8*)(x + (size_t)s6 * NF))[c];
        u16x8 v7 = ((const u16x8*)(x + (size_t)s7 * NF))[c];
#pragma unroll
        for (int r = 0; r < 8; ++r)
            acc[r] += ((bf2f(v0[r]) + bf2f(v1[r])) + (bf2f(v2[r]) + bf2f(v3[r])))
                    + ((bf2f(v4[r]) + bf2f(v5[r])) + (bf2f(v6[r]) + bf2f(v7[r])));
    }
    if (j + 4 <= end) {
        int s0 = eid[j + 0], s1 = eid[j + 1], s2 = eid[j + 2], s3 = eid[j + 3];
        u16x8 v0 = ((const u16x8*)(x + (size_t)s0 * NF))[c];
        u16x8 v1 = ((const u16x8*)(x + (size_t)s1 * NF))[c];
        u16x8 v2 = ((const u16x8*)(x + (size_t)s2 * NF))[c];
        u16x8 v3 = ((const u16x8*)(x + (size_t)s3 * NF))[c];
#pragma unroll
        for (int r = 0; r < 8; ++r)
            acc[r] += (bf2f(v0[r]) + bf2f(v1[r])) + (bf2f(v2[r]) + bf2f(v3[r]));
        j += 4;
    }
    for (; j < end; ++j) {
        int s0 = eid[j];
        u16x8 v0 = ((const u16x8*)(x + (size_t)s0 * NF))[c];
#pragma unroll
        for (int r = 0; r < 8; ++r) acc[r] += bf2f(v0[r]);
    }
}

// ---------------------------------------------------------------------------
// Fused prep + split. r7: per-wave histogram/cursor replication (hcnt_w) —
// removes cross-wave same-address LDS-atomic serialization (mean 16-way ->
// ~4-way within a wave; m136: 16-way costs 5.7x). gcur zeroed by prior memset.
// ---------------------------------------------------------------------------
__global__ __launch_bounds__(256) void split_prep_kernel(
    const int* __restrict__ src, const int* __restrict__ dst,
    unsigned int* __restrict__ records, int* __restrict__ gcur,
    const float* __restrict__ feat, unsigned short* __restrict__ featbf,
    const float* __restrict__ W1, const float* __restrict__ W2,
    unsigned short* __restrict__ Wt1, unsigned short* __restrict__ Wt2,
    float* __restrict__ sums, int ne, int nv4) {
    __shared__ unsigned int stage[SPLIT_TILE];  // 16 KB
    __shared__ int hcnt_w[4][NPARTS];           // 4 KB; hist then per-wave cursor
    __shared__ int hcnt[NPARTS];
    __shared__ int hscan[NPARTS];
    __shared__ int hg[NPARTS];
    int t = threadIdx.x;
    int gtid = blockIdx.x * 256 + t;
    int nthreads = gridDim.x * 256;

    // ---- prep (grid-stride over all blocks) ----
    for (int i = gtid; i < nv4; i += nthreads) {
        float4 v = ((const float4*)feat)[i];
        ushort4 o;
        o.x = f2bf(v.x); o.y = f2bf(v.y); o.z = f2bf(v.z); o.w = f2bf(v.w);
        ((ushort4*)featbf)[i] = o;
    }
    for (int i = gtid; i < 2 * NF * NF; i += nthreads) {
        const float* W = (i < NF * NF) ? W1 : W2;
        unsigned short* Wt = (i < NF * NF) ? Wt1 : Wt2;
        int id = i & (NF * NF - 1);
        int f = id >> 7;
        int k = id & 127;
        Wt[f * NF + k] = f2bf(W[k * NF + f]);
    }
    for (int i = gtid; i < NGRAPHS * NF; i += nthreads) sums[i] = 0.f;

    // ---- split ----
    int tile0 = blockIdx.x * SPLIT_TILE;
    int cnt = min(SPLIT_TILE, ne - tile0);
    if (cnt <= 0) return;
    hcnt_w[0][t] = 0; hcnt_w[1][t] = 0; hcnt_w[2][t] = 0; hcnt_w[3][t] = 0;
    __syncthreads();
    int wv = t >> 6;
    // pass 1: load (dst,src) into registers + per-wave histogram
    int dv[16], sv[16];
#pragma unroll
    for (int k2 = 0; k2 < 16; ++k2) {
        int i = k2 * 256 + t;
        if (i < cnt) {
            dv[k2] = dst[tile0 + i];
            sv[k2] = src[tile0 + i];
            atomicAdd(&hcnt_w[wv][dv[k2] >> PART_SHIFT], 1);
        }
    }
    __syncthreads();
    // combine per-wave counts (column t private to thread t)
    int c0 = hcnt_w[0][t], c1 = hcnt_w[1][t], c2 = hcnt_w[2][t], c3 = hcnt_w[3][t];
    hcnt[t] = c0 + c1 + c2 + c3;
    hscan[t] = hcnt[t];
    __syncthreads();
    // inclusive Hillis-Steele scan of 256 counters
    for (int off = 1; off < NPARTS; off <<= 1) {
        int v = (t >= off) ? hscan[t - off] : 0;
        __syncthreads();
        hscan[t] += v;
        __syncthreads();
    }
    int excl = hscan[t] - hcnt[t];
    hcnt_w[0][t] = excl;
    hcnt_w[1][t] = excl + c0;
    hcnt_w[2][t] = excl + c0 + c1;
    hcnt_w[3][t] = excl + c0 + c1 + c2;
    hg[t] = hcnt[t] ? atomicAdd(&gcur[t], hcnt[t]) : 0;
    __syncthreads();
    // pass 2: place packed records via per-wave cursors
#pragma unroll
    for (int k2 = 0; k2 < 16; ++k2) {
        int i = k2 * 256 + t;
        if (i < cnt) {
            int d = dv[k2];
            int pos = atomicAdd(&hcnt_w[wv][d >> PART_SHIFT], 1);
            stage[pos] = (((unsigned int)(d & (PART_NODES - 1))) << SRC_BITS)
                         | (unsigned int)sv[k2];
        }
    }
    __syncthreads();
    // flush: quarter-wave (16 lanes) per partition, 16 partitions concurrent
    int grp = t >> 4;
    int lt = t & 15;
    for (int p = grp; p < NPARTS; p += 16) {
        int c = hcnt[p];
        if (c == 0) continue;
        int b = hscan[p] - c;
        int g = hg[p];
        if (g + c > PART_CAP) c = max(0, PART_CAP - g);   // never in practice
        unsigned int* outp = records + (size_t)p * PART_CAP + g;
        for (int i = lt; i < c; i += 16) outp[i] = stage[b + i];
    }
}

// ---------------------------------------------------------------------------
// Per-partition CSR build. r7: per-wave degree/cursor replication (deg_w) —
// same contention cut as the split (degree mean 16 -> ~4-way per wave).
// ---------------------------------------------------------------------------
__global__ __launch_bounds__(256) void build_kernel(
    const unsigned int* __restrict__ records, const int* __restrict__ gcur,
    int* __restrict__ offs, int* __restrict__ eid, int n) {
    __shared__ int deg_w[4][PART_NODES];  // 8 KB; hist then per-wave cursor
    __shared__ int ps[NPARTS];            // 1 KB
    __shared__ int wsum[4];
    __shared__ unsigned int rc[PART_CAP]; // 36 KB record cache
    int t = threadIdx.x;
    int p = blockIdx.x;

    // partition-base scan (inclusive)
    ps[t] = min(gcur[t], PART_CAP);
    __syncthreads();
    for (int off = 1; off < NPARTS; off <<= 1) {
        int v = (t >= off) ? ps[t - off] : 0;
        __syncthreads();
        ps[t] += v;
        __syncthreads();
    }
    int L = min(gcur[p], PART_CAP);
    int base_g = ps[p] - L;
    if (p == 0 && t == 0) offs[n] = ps[NPARTS - 1];

    int lo = p << PART_SHIFT;
    int nn = min(n - lo, PART_NODES);
    if (nn <= 0) return;

#pragma unroll
    for (int w2 = 0; w2 < 4; ++w2) { deg_w[w2][t] = 0; deg_w[w2][t + 256] = 0; }
    __syncthreads();

    int wv = t >> 6;
    const unsigned int* rp = records + (size_t)p * PART_CAP;
    for (int i = t; i < L; i += 256) {
        unsigned int r = rp[i];
        rc[i] = r;
        atomicAdd(&deg_w[wv][r >> SRC_BITS], 1);
    }
    __syncthreads();

    // block exclusive scan over combined deg[0..512) (2 elems/thread)
    int a0 = deg_w[0][2 * t],     a1 = deg_w[1][2 * t];
    int a2 = deg_w[2][2 * t],     a3 = deg_w[3][2 * t];
    int b0 = deg_w[0][2 * t + 1], b1 = deg_w[1][2 * t + 1];
    int b2 = deg_w[2][2 * t + 1], b3 = deg_w[3][2 * t + 1];
    int v0 = a0 + a1 + a2 + a3;
    int v1 = b0 + b1 + b2 + b3;
    int tsum = v0 + v1;
    int lane = t & 63, w = t >> 6;
    int sc = tsum;
    for (int off = 1; off < 64; off <<= 1) {
        int u = __shfl_up(sc, off, 64);
        if (lane >= off) sc += u;
    }
    if (lane == 63) wsum[w] = sc;
    __syncthreads();
    if (t == 0) {
        int a = 0;
        for (int k = 0; k < 4; ++k) { int v = wsum[k]; wsum[k] = a; a += v; }
    }
    __syncthreads();
    int run = sc - tsum + wsum[w];
    deg_w[0][2 * t] = run;
    deg_w[1][2 * t] = run + a0;
    deg_w[2][2 * t] = run + a0 + a1;
    deg_w[3][2 * t] = run + a0 + a1 + a2;
    if (2 * t < nn) offs[lo + 2 * t] = base_g + run;
    run += v0;
    deg_w[0][2 * t + 1] = run;
    deg_w[1][2 * t + 1] = run + b0;
    deg_w[2][2 * t + 1] = run + b0 + b1;
    deg_w[3][2 * t + 1] = run + b0 + b1 + b2;
    if (2 * t + 1 < nn) offs[lo + 2 * t + 1] = base_g + run;
    __syncthreads();

    // fill eid from the LDS cache via per-wave cursors
    for (int i = t; i < L; i += 256) {
        unsigned int r = rc[i];
        int pos = atomicAdd(&deg_w[wv][r >> SRC_BITS], 1);
        eid[base_g + pos] = (int)(r & ((1u << SRC_BITS) - 1));
    }
}

// ---------------------------------------------------------------------------
// Fused gather + MFMA GEMM (layer 1), round-1 register path (unchanged).
// ---------------------------------------------------------------------------
__global__ __launch_bounds__(256) void gather_gemm1(
    const unsigned short* __restrict__ x, const int* __restrict__ offs,
    const int* __restrict__ eid, const unsigned short* __restrict__ Wt,
    const float* __restrict__ bias, unsigned short* __restrict__ out, int n) {
    __shared__ unsigned short As[16 * AS_STRIDE];
    int wave = threadIdx.x >> 6;
    int lane = threadIdx.x & 63;
    int q = lane >> 4;        // node selector within wave
    int c = lane & 15;        // 16B chunk / m-index
    int node_base = blockIdx.x * 16;
    int row = wave * 4 + q;   // 0..15

    float acc[8];
    gather_node(x, offs, eid, node_base + row, n, c, acc);
    {
        u16x8 o;
#pragma unroll
        for (int r = 0; r < 8; ++r) o[r] = f2bf(acc[r]);
        *(u16x8*)(&As[row * AS_STRIDE + c * 8]) = o;
    }
    __syncthreads();

    int m16 = c;
    int n0 = wave * 32;
    const unsigned short* b0r = Wt + (size_t)(n0 + m16) * NF + q * 8;
    const unsigned short* b1r = b0r + 16 * NF;
    f32x4 acc0 = {0.f, 0.f, 0.f, 0.f};
    f32x4 acc1 = {0.f, 0.f, 0.f, 0.f};
#pragma unroll
    for (int kk = 0; kk < 4; ++kk) {
        bf16x8 a  = *(const bf16x8*)(&As[m16 * AS_STRIDE + kk * 32 + q * 8]);
        bf16x8 b0 = *(const bf16x8*)(b0r + kk * 32);
        bf16x8 b1 = *(const bf16x8*)(b1r + kk * 32);
        acc0 = __builtin_amdgcn_mfma_f32_16x16x32_bf16(a, b0, acc0, 0, 0, 0);
        acc1 = __builtin_amdgcn_mfma_f32_16x16x32_bf16(a, b1, acc1, 0, 0, 0);
    }
    float bias0 = bias[n0 + m16];
    float bias1 = bias[n0 + 16 + m16];
#pragma unroll
    for (int r = 0; r < 4; ++r) {
        int node = node_base + q * 4 + r;
        if (node >= n) break;
        unsigned short* o = out + (size_t)node * NF;
        o[n0 + m16]      = f2bf(fmaxf(acc0[r] + bias0, 0.f));
        o[n0 + 16 + m16] = f2bf(fmaxf(acc1[r] + bias1, 0.f));
    }
}

__device__ __forceinline__ int lower_bound_i(const int* a, int n, int key) {
    int lo = 0, hi = n;
    while (lo < hi) {
        int mid = (lo + hi) >> 1;
        if (a[mid] < key) lo = mid + 1; else hi = mid;
    }
    return lo;
}

// ---------------------------------------------------------------------------
// Fused gather + MFMA GEMM (layer 2) + pool epilogue + LAST-BLOCK final
// projection (r7: removes the final_kernel dispatch + gap). Ordering: the
// __syncthreads() before the done-increment drains every wave's sums-atomics
// (compiler emits s_waitcnt vmcnt(0) before s_barrier); the ACQ_REL device-
// scope fetch_add orders publication; the last block reads sums with device-
// scope atomic loads. No __threadfence (r12 hazard).
// ---------------------------------------------------------------------------
__global__ __launch_bounds__(256) void gather_gemm2_pool_final(
    const unsigned short* __restrict__ x, const int* __restrict__ offs,
    const int* __restrict__ eid, const unsigned short* __restrict__ Wt,
    const float* __restrict__ bias, const int* __restrict__ gid,
    float* __restrict__ sums, int* __restrict__ done_cnt,
    const float* __restrict__ Wp, const float* __restrict__ bp,
    float* __restrict__ out, int n) {
    __shared__ unsigned short As[16 * AS_STRIDE];
    __shared__ float hblk[16][NF];
    __shared__ int bnd[NGRAPHS + 1];
    __shared__ int is_last;
    int wave = threadIdx.x >> 6;
    int lane = threadIdx.x & 63;
    int q = lane >> 4;
    int c = lane & 15;
    int node_base = blockIdx.x * 16;
    int row = wave * 4 + q;

    float acc[8];
    gather_node(x, offs, eid, node_base + row, n, c, acc);
    {
        u16x8 o;
#pragma unroll
        for (int r = 0; r < 8; ++r) o[r] = f2bf(acc[r]);
        *(u16x8*)(&As[row * AS_STRIDE + c * 8]) = o;
    }
    __syncthreads();

    int m16 = c;
    int n0 = wave * 32;
    const unsigned short* b0r = Wt + (size_t)(n0 + m16) * NF + q * 8;
    const unsigned short* b1r = b0r + 16 * NF;
    f32x4 acc0 = {0.f, 0.f, 0.f, 0.f};
    f32x4 acc1 = {0.f, 0.f, 0.f, 0.f};
#pragma unroll
    for (int kk = 0; kk < 4; ++kk) {
        bf16x8 a  = *(const bf16x8*)(&As[m16 * AS_STRIDE + kk * 32 + q * 8]);
        bf16x8 b0 = *(const bf16x8*)(b0r + kk * 32);
        bf16x8 b1 = *(const bf16x8*)(b1r + kk * 32);
        acc0 = __builtin_amdgcn_mfma_f32_16x16x32_bf16(a, b0, acc0, 0, 0, 0);
        acc1 = __builtin_amdgcn_mfma_f32_16x16x32_bf16(a, b1, acc1, 0, 0, 0);
    }
    float bias0 = bias[n0 + m16];
    float bias1 = bias[n0 + 16 + m16];
#pragma unroll
    for (int r = 0; r < 4; ++r) {
        int rr = q * 4 + r;
        hblk[rr][n0 + m16]      = fmaxf(acc0[r] + bias0, 0.f);
        hblk[rr][n0 + 16 + m16] = fmaxf(acc1[r] + bias1, 0.f);
    }
    __syncthreads();

    int t = threadIdx.x;
    if (t < NF) {
        float accp = 0.f;
        int cur = -1;
        int lim = min(16, n - node_base);
        for (int i = 0; i < lim; ++i) {
            int g = gid[node_base + i];
            if (g != cur) {
                if (cur >= 0) atomicAdd(&sums[cur * NF + t], accp);
                accp = 0.f;
                cur = g;
            }
            accp += bf2f(f2bf(hblk[i][t]));    // keep bf16 rounding of h2 path
        }
        if (cur >= 0) atomicAdd(&sums[cur * NF + t], accp);
    }

    // ---- last-block-done final projection ----
    __syncthreads();   // drains all waves' sums atomics (vmcnt(0) before barrier)
    if (t == 0) {
        int prev = __hip_atomic_fetch_add(done_cnt, 1, __ATOMIC_ACQ_REL,
                                          __HIP_MEMORY_SCOPE_AGENT);
        is_last = (prev == (int)gridDim.x - 1);
    }
    __syncthreads();
    if (!is_last) return;

    if (t <= NGRAPHS) bnd[t] = lower_bound_i(gid, n, t);
    __syncthreads();
    for (int g = wave; g < NGRAPHS; g += 4) {
        float cntf = fmaxf((float)(bnd[g + 1] - bnd[g]), 1.0f);
        float inv = 1.0f / cntf;
        float s0 = __hip_atomic_load(&sums[g * NF + lane], __ATOMIC_RELAXED,
                                     __HIP_MEMORY_SCOPE_AGENT) * inv;
        float s1 = __hip_atomic_load(&sums[g * NF + 64 + lane], __ATOMIC_RELAXED,
                                     __HIP_MEMORY_SCOPE_AGENT) * inv;
#pragma unroll
        for (int cc = 0; cc < NCLS; ++cc) {
            float pv = s0 * Wp[lane * NCLS + cc] + s1 * Wp[(64 + lane) * NCLS + cc];
#pragma unroll
            for (int m = 1; m < 64; m <<= 1) pv += __shfl_xor(pv, m, 64);
            if (lane == 0) out[g * NCLS + cc] = pv + bp[cc];
        }
    }
}

extern "C" void kernel_launch(void* const* d_in, const int* in_sizes, int n_in,
                              void* d_out, int out_size, void* d_ws, size_t ws_size,
                              hipStream_t stream) {
    const float* feat = (const float*)d_in[0];
    const float* W1   = (const float*)d_in[1];
    const float* b1   = (const float*)d_in[2];
    const float* W2   = (const float*)d_in[3];
    const float* b2   = (const float*)d_in[4];
    const float* Wp   = (const float*)d_in[5];
    const float* bp   = (const float*)d_in[6];
    const int*   src  = (const int*)d_in[7];
    const int*   dst  = (const int*)d_in[8];
    const int*   gid  = (const int*)d_in[9];

    int ne = in_sizes[7];
    int n  = in_sizes[9];

    // Workspace (16B-aligned segments):
    unsigned short* featbf = (unsigned short*)d_ws;                  // n*128 u16
    unsigned short* h1     = featbf + (size_t)n * NF;                // n*128 u16
    unsigned int* records = (unsigned int*)(h1 + (size_t)n * NF);    // 256*PART_CAP u32
    int* eid      = (int*)(records + (size_t)NPARTS * PART_CAP);     // ne
    float* sums   = (float*)(eid + ne);                              // 64*128
    int* gcur     = (int*)(sums + NGRAPHS * NF);                     // NPARTS + done
    int* done_cnt = gcur + NPARTS;                                   // 1 (+3 pad)
    unsigned short* Wt1 = (unsigned short*)(gcur + NPARTS + 4);      // 128*128
    unsigned short* Wt2 = Wt1 + NF * NF;                             // 128*128
    int* offs     = (int*)(Wt2 + NF * NF);                           // n+1

    int nv4 = n * NF / 4;
    int splitblocks = (ne + SPLIT_TILE - 1) / SPLIT_TILE;
    int buildblocks = (n + PART_NODES - 1) >> PART_SHIFT;
    int ggblocks = (n + 15) / 16;

    hipMemsetAsync(gcur, 0, (NPARTS + 1) * sizeof(int), stream);
    split_prep_kernel<<<splitblocks, 256, 0, stream>>>(
        src, dst, records, gcur, feat, featbf, W1, W2, Wt1, Wt2, sums, ne, nv4);
    build_kernel<<<buildblocks, 256, 0, stream>>>(records, gcur, offs, eid, n);

    gather_gemm1<<<ggblocks, 256, 0, stream>>>(featbf, offs, eid, Wt1, b1, h1, n);
    gather_gemm2_pool_final<<<ggblocks, 256, 0, stream>>>(
        h1, offs, eid, Wt2, b2, gid, sums, done_cnt, Wp, bp, (float*)d_out, n);
}

// Round 9
// 306.995 us; speedup vs baseline: 1.5991x; 1.5991x over previous
//
#include <hip/hip_runtime.h>

#define NF 128
#define NGRAPHS 64
#define NCLS 10
#define NPARTS 256         // dst partitions, 512 nodes each (n <= 131072)
#define PART_SHIFT 9
#define PART_NODES 512
#define PART_CAP 9216      // mean 6250 + ~37 sigma slack
#define SPLIT_TILE 4096
#define AS_STRIDE 136      // bf16 elems per LDS A-row (128 + 8 pad)
#define SRC_BITS 17        // src < 2^17 (n <= 131072); record = dlocal<<17 | src

typedef __attribute__((ext_vector_type(8))) short bf16x8;          // MFMA frag
typedef __attribute__((ext_vector_type(4))) float f32x4;
typedef __attribute__((ext_vector_type(8))) unsigned short u16x8;  // 16B row chunk

__device__ __forceinline__ float bf2f(unsigned short u) {
    union { unsigned int i; float f; } v; v.i = ((unsigned int)u) << 16; return v.f;
}
__device__ __forceinline__ unsigned short f2bf(float f) {
    union { float f; unsigned int i; } v; v.f = f;
    unsigned int lsb = (v.i >> 16) & 1;
    v.i += 0x7fffu + lsb;                 // RNE
    return (unsigned short)(v.i >> 16);
}

// ---------------------------------------------------------------------------
// Register-path per-node gather (round-1 form, best measured: 76 us/layer =
// 5.4 TB/s delivered = 86% of streaming ceiling; invariant to MLP depth /
// L2 residency / LDS-DMA — r0/r2/r3 A/B). Needs >~40% occupancy (r6).
// NO device-scope fences/acq-rel atomics anywhere in this pipeline:
// r12 (__threadfence) and r7 (ACQ_REL agent atomic) both = L2 cache-
// maintenance per block = 3.6-8x regression.
// ---------------------------------------------------------------------------
__device__ __forceinline__ void gather_node(
    const unsigned short* __restrict__ x, const int* __restrict__ offs,
    const int* __restrict__ eid, int node, int n, int c, float acc[8]) {
#pragma unroll
    for (int r = 0; r < 8; ++r) acc[r] = 0.f;
    if (node >= n) return;
    int j = offs[node];
    int end = offs[node + 1];
    for (; j + 8 <= end; j += 8) {
        int s0 = eid[j + 0], s1 = eid[j + 1], s2 = eid[j + 2], s3 = eid[j + 3];
        int s4 = eid[j + 4], s5 = eid[j + 5], s6 = eid[j + 6], s7 = eid[j + 7];
        u16x8 v0 = ((const u16x8*)(x + (size_t)s0 * NF))[c];
        u16x8 v1 = ((const u16x8*)(x + (size_t)s1 * NF))[c];
        u16x8 v2 = ((const u16x8*)(x + (size_t)s2 * NF))[c];
        u16x8 v3 = ((const u16x8*)(x + (size_t)s3 * NF))[c];
        u16x8 v4 = ((const u16x8*)(x + (size_t)s4 * NF))[c];
        u16x8 v5 = ((const u16x8*)(x + (size_t)s5 * NF))[c];
        u16x8 v6 = ((const u16x8*)(x + (size_t)s6 * NF))[c];
        u16x8 v7 = ((const u16x8*)(x + (size_t)s7 * NF))[c];
#pragma unroll
        for (int r = 0; r < 8; ++r)
            acc[r] += ((bf2f(v0[r]) + bf2f(v1[r])) + (bf2f(v2[r]) + bf2f(v3[r])))
                    + ((bf2f(v4[r]) + bf2f(v5[r])) + (bf2f(v6[r]) + bf2f(v7[r])));
    }
    if (j + 4 <= end) {
        int s0 = eid[j + 0], s1 = eid[j + 1], s2 = eid[j + 2], s3 = eid[j + 3];
        u16x8 v0 = ((const u16x8*)(x + (size_t)s0 * NF))[c];
        u16x8 v1 = ((const u16x8*)(x + (size_t)s1 * NF))[c];
        u16x8 v2 = ((const u16x8*)(x + (size_t)s2 * NF))[c];
        u16x8 v3 = ((const u16x8*)(x + (size_t)s3 * NF))[c];
#pragma unroll
        for (int r = 0; r < 8; ++r)
            acc[r] += (bf2f(v0[r]) + bf2f(v1[r])) + (bf2f(v2[r]) + bf2f(v3[r]));
        j += 4;
    }
    for (; j < end; ++j) {
        int s0 = eid[j];
        u16x8 v0 = ((const u16x8*)(x + (size_t)s0 * NF))[c];
#pragma unroll
        for (int r = 0; r < 8; ++r) acc[r] += bf2f(v0[r]);
    }
}

// ---------------------------------------------------------------------------
// Fused prep + split with per-wave histogram/cursor replication (hcnt_w):
// cross-wave same-address LDS-atomic serialization removed (mean 16-way ->
// ~4-way within a wave; m136: 16-way costs 5.7x). gcur zeroed by prior memset.
// ---------------------------------------------------------------------------
__global__ __launch_bounds__(256) void split_prep_kernel(
    const int* __restrict__ src, const int* __restrict__ dst,
    unsigned int* __restrict__ records, int* __restrict__ gcur,
    const float* __restrict__ feat, unsigned short* __restrict__ featbf,
    const float* __restrict__ W1, const float* __restrict__ W2,
    unsigned short* __restrict__ Wt1, unsigned short* __restrict__ Wt2,
    float* __restrict__ sums, int ne, int nv4) {
    __shared__ unsigned int stage[SPLIT_TILE];  // 16 KB
    __shared__ int hcnt_w[4][NPARTS];           // 4 KB; hist then per-wave cursor
    __shared__ int hcnt[NPARTS];
    __shared__ int hscan[NPARTS];
    __shared__ int hg[NPARTS];
    int t = threadIdx.x;
    int gtid = blockIdx.x * 256 + t;
    int nthreads = gridDim.x * 256;

    // ---- prep (grid-stride over all blocks) ----
    for (int i = gtid; i < nv4; i += nthreads) {
        float4 v = ((const float4*)feat)[i];
        ushort4 o;
        o.x = f2bf(v.x); o.y = f2bf(v.y); o.z = f2bf(v.z); o.w = f2bf(v.w);
        ((ushort4*)featbf)[i] = o;
    }
    for (int i = gtid; i < 2 * NF * NF; i += nthreads) {
        const float* W = (i < NF * NF) ? W1 : W2;
        unsigned short* Wt = (i < NF * NF) ? Wt1 : Wt2;
        int id = i & (NF * NF - 1);
        int f = id >> 7;
        int k = id & 127;
        Wt[f * NF + k] = f2bf(W[k * NF + f]);
    }
    for (int i = gtid; i < NGRAPHS * NF; i += nthreads) sums[i] = 0.f;

    // ---- split ----
    int tile0 = blockIdx.x * SPLIT_TILE;
    int cnt = min(SPLIT_TILE, ne - tile0);
    if (cnt <= 0) return;
    hcnt_w[0][t] = 0; hcnt_w[1][t] = 0; hcnt_w[2][t] = 0; hcnt_w[3][t] = 0;
    __syncthreads();
    int wv = t >> 6;
    // pass 1: load (dst,src) into registers + per-wave histogram
    int dv[16], sv[16];
#pragma unroll
    for (int k2 = 0; k2 < 16; ++k2) {
        int i = k2 * 256 + t;
        if (i < cnt) {
            dv[k2] = dst[tile0 + i];
            sv[k2] = src[tile0 + i];
            atomicAdd(&hcnt_w[wv][dv[k2] >> PART_SHIFT], 1);
        }
    }
    __syncthreads();
    // combine per-wave counts (column t private to thread t)
    int c0 = hcnt_w[0][t], c1 = hcnt_w[1][t], c2 = hcnt_w[2][t], c3 = hcnt_w[3][t];
    hcnt[t] = c0 + c1 + c2 + c3;
    hscan[t] = hcnt[t];
    __syncthreads();
    // inclusive Hillis-Steele scan of 256 counters
    for (int off = 1; off < NPARTS; off <<= 1) {
        int v = (t >= off) ? hscan[t - off] : 0;
        __syncthreads();
        hscan[t] += v;
        __syncthreads();
    }
    int excl = hscan[t] - hcnt[t];
    hcnt_w[0][t] = excl;
    hcnt_w[1][t] = excl + c0;
    hcnt_w[2][t] = excl + c0 + c1;
    hcnt_w[3][t] = excl + c0 + c1 + c2;
    hg[t] = hcnt[t] ? atomicAdd(&gcur[t], hcnt[t]) : 0;
    __syncthreads();
    // pass 2: place packed records via per-wave cursors
#pragma unroll
    for (int k2 = 0; k2 < 16; ++k2) {
        int i = k2 * 256 + t;
        if (i < cnt) {
            int d = dv[k2];
            int pos = atomicAdd(&hcnt_w[wv][d >> PART_SHIFT], 1);
            stage[pos] = (((unsigned int)(d & (PART_NODES - 1))) << SRC_BITS)
                         | (unsigned int)sv[k2];
        }
    }
    __syncthreads();
    // flush: quarter-wave (16 lanes) per partition, 16 partitions concurrent
    int grp = t >> 4;
    int lt = t & 15;
    for (int p = grp; p < NPARTS; p += 16) {
        int c = hcnt[p];
        if (c == 0) continue;
        int b = hscan[p] - c;
        int g = hg[p];
        if (g + c > PART_CAP) c = max(0, PART_CAP - g);   // never in practice
        unsigned int* outp = records + (size_t)p * PART_CAP + g;
        for (int i = lt; i < c; i += 16) outp[i] = stage[b + i];
    }
}

// ---------------------------------------------------------------------------
// Per-partition CSR build with per-wave degree/cursor replication (deg_w).
// ---------------------------------------------------------------------------
__global__ __launch_bounds__(256) void build_kernel(
    const unsigned int* __restrict__ records, const int* __restrict__ gcur,
    int* __restrict__ offs, int* __restrict__ eid, int n) {
    __shared__ int deg_w[4][PART_NODES];  // 8 KB; hist then per-wave cursor
    __shared__ int ps[NPARTS];            // 1 KB
    __shared__ int wsum[4];
    __shared__ unsigned int rc[PART_CAP]; // 36 KB record cache
    int t = threadIdx.x;
    int p = blockIdx.x;

    // partition-base scan (inclusive)
    ps[t] = min(gcur[t], PART_CAP);
    __syncthreads();
    for (int off = 1; off < NPARTS; off <<= 1) {
        int v = (t >= off) ? ps[t - off] : 0;
        __syncthreads();
        ps[t] += v;
        __syncthreads();
    }
    int L = min(gcur[p], PART_CAP);
    int base_g = ps[p] - L;
    if (p == 0 && t == 0) offs[n] = ps[NPARTS - 1];

    int lo = p << PART_SHIFT;
    int nn = min(n - lo, PART_NODES);
    if (nn <= 0) return;

#pragma unroll
    for (int w2 = 0; w2 < 4; ++w2) { deg_w[w2][t] = 0; deg_w[w2][t + 256] = 0; }
    __syncthreads();

    int wv = t >> 6;
    const unsigned int* rp = records + (size_t)p * PART_CAP;
    for (int i = t; i < L; i += 256) {
        unsigned int r = rp[i];
        rc[i] = r;
        atomicAdd(&deg_w[wv][r >> SRC_BITS], 1);
    }
    __syncthreads();

    // block exclusive scan over combined deg[0..512) (2 elems/thread)
    int a0 = deg_w[0][2 * t],     a1 = deg_w[1][2 * t];
    int a2 = deg_w[2][2 * t],     a3 = deg_w[3][2 * t];
    int b0 = deg_w[0][2 * t + 1], b1 = deg_w[1][2 * t + 1];
    int b2 = deg_w[2][2 * t + 1], b3 = deg_w[3][2 * t + 1];
    int v0 = a0 + a1 + a2 + a3;
    int v1 = b0 + b1 + b2 + b3;
    int tsum = v0 + v1;
    int lane = t & 63, w = t >> 6;
    int sc = tsum;
    for (int off = 1; off < 64; off <<= 1) {
        int u = __shfl_up(sc, off, 64);
        if (lane >= off) sc += u;
    }
    if (lane == 63) wsum[w] = sc;
    __syncthreads();
    if (t == 0) {
        int a = 0;
        for (int k = 0; k < 4; ++k) { int v = wsum[k]; wsum[k] = a; a += v; }
    }
    __syncthreads();
    int run = sc - tsum + wsum[w];
    deg_w[0][2 * t] = run;
    deg_w[1][2 * t] = run + a0;
    deg_w[2][2 * t] = run + a0 + a1;
    deg_w[3][2 * t] = run + a0 + a1 + a2;
    if (2 * t < nn) offs[lo + 2 * t] = base_g + run;
    run += v0;
    deg_w[0][2 * t + 1] = run;
    deg_w[1][2 * t + 1] = run + b0;
    deg_w[2][2 * t + 1] = run + b0 + b1;
    deg_w[3][2 * t + 1] = run + b0 + b1 + b2;
    if (2 * t + 1 < nn) offs[lo + 2 * t + 1] = base_g + run;
    __syncthreads();

    // fill eid from the LDS cache via per-wave cursors
    for (int i = t; i < L; i += 256) {
        unsigned int r = rc[i];
        int pos = atomicAdd(&deg_w[wv][r >> SRC_BITS], 1);
        eid[base_g + pos] = (int)(r & ((1u << SRC_BITS) - 1));
    }
}

// ---------------------------------------------------------------------------
// Fused gather + MFMA GEMM (layer 1), round-1 register path (unchanged).
// ---------------------------------------------------------------------------
__global__ __launch_bounds__(256) void gather_gemm1(
    const unsigned short* __restrict__ x, const int* __restrict__ offs,
    const int* __restrict__ eid, const unsigned short* __restrict__ Wt,
    const float* __restrict__ bias, unsigned short* __restrict__ out, int n) {
    __shared__ unsigned short As[16 * AS_STRIDE];
    int wave = threadIdx.x >> 6;
    int lane = threadIdx.x & 63;
    int q = lane >> 4;        // node selector within wave
    int c = lane & 15;        // 16B chunk / m-index
    int node_base = blockIdx.x * 16;
    int row = wave * 4 + q;   // 0..15

    float acc[8];
    gather_node(x, offs, eid, node_base + row, n, c, acc);
    {
        u16x8 o;
#pragma unroll
        for (int r = 0; r < 8; ++r) o[r] = f2bf(acc[r]);
        *(u16x8*)(&As[row * AS_STRIDE + c * 8]) = o;
    }
    __syncthreads();

    int m16 = c;
    int n0 = wave * 32;
    const unsigned short* b0r = Wt + (size_t)(n0 + m16) * NF + q * 8;
    const unsigned short* b1r = b0r + 16 * NF;
    f32x4 acc0 = {0.f, 0.f, 0.f, 0.f};
    f32x4 acc1 = {0.f, 0.f, 0.f, 0.f};
#pragma unroll
    for (int kk = 0; kk < 4; ++kk) {
        bf16x8 a  = *(const bf16x8*)(&As[m16 * AS_STRIDE + kk * 32 + q * 8]);
        bf16x8 b0 = *(const bf16x8*)(b0r + kk * 32);
        bf16x8 b1 = *(const bf16x8*)(b1r + kk * 32);
        acc0 = __builtin_amdgcn_mfma_f32_16x16x32_bf16(a, b0, acc0, 0, 0, 0);
        acc1 = __builtin_amdgcn_mfma_f32_16x16x32_bf16(a, b1, acc1, 0, 0, 0);
    }
    float bias0 = bias[n0 + m16];
    float bias1 = bias[n0 + 16 + m16];
#pragma unroll
    for (int r = 0; r < 4; ++r) {
        int node = node_base + q * 4 + r;
        if (node >= n) break;
        unsigned short* o = out + (size_t)node * NF;
        o[n0 + m16]      = f2bf(fmaxf(acc0[r] + bias0, 0.f));
        o[n0 + 16 + m16] = f2bf(fmaxf(acc1[r] + bias1, 0.f));
    }
}

// ---------------------------------------------------------------------------
// Fused gather + MFMA GEMM (layer 2) + pool epilogue (round-1 form).
// Plain device atomicAdd only — no fences, no acq/rel (r12/r7 hazard).
// ---------------------------------------------------------------------------
__global__ __launch_bounds__(256) void gather_gemm2_pool(
    const unsigned short* __restrict__ x, const int* __restrict__ offs,
    const int* __restrict__ eid, const unsigned short* __restrict__ Wt,
    const float* __restrict__ bias, const int* __restrict__ gid,
    float* __restrict__ sums, int n) {
    __shared__ unsigned short As[16 * AS_STRIDE];
    __shared__ float hblk[16][NF];
    int wave = threadIdx.x >> 6;
    int lane = threadIdx.x & 63;
    int q = lane >> 4;
    int c = lane & 15;
    int node_base = blockIdx.x * 16;
    int row = wave * 4 + q;

    float acc[8];
    gather_node(x, offs, eid, node_base + row, n, c, acc);
    {
        u16x8 o;
#pragma unroll
        for (int r = 0; r < 8; ++r) o[r] = f2bf(acc[r]);
        *(u16x8*)(&As[row * AS_STRIDE + c * 8]) = o;
    }
    __syncthreads();

    int m16 = c;
    int n0 = wave * 32;
    const unsigned short* b0r = Wt + (size_t)(n0 + m16) * NF + q * 8;
    const unsigned short* b1r = b0r + 16 * NF;
    f32x4 acc0 = {0.f, 0.f, 0.f, 0.f};
    f32x4 acc1 = {0.f, 0.f, 0.f, 0.f};
#pragma unroll
    for (int kk = 0; kk < 4; ++kk) {
        bf16x8 a  = *(const bf16x8*)(&As[m16 * AS_STRIDE + kk * 32 + q * 8]);
        bf16x8 b0 = *(const bf16x8*)(b0r + kk * 32);
        bf16x8 b1 = *(const bf16x8*)(b1r + kk * 32);
        acc0 = __builtin_amdgcn_mfma_f32_16x16x32_bf16(a, b0, acc0, 0, 0, 0);
        acc1 = __builtin_amdgcn_mfma_f32_16x16x32_bf16(a, b1, acc1, 0, 0, 0);
    }
    float bias0 = bias[n0 + m16];
    float bias1 = bias[n0 + 16 + m16];
#pragma unroll
    for (int r = 0; r < 4; ++r) {
        int rr = q * 4 + r;
        hblk[rr][n0 + m16]      = fmaxf(acc0[r] + bias0, 0.f);
        hblk[rr][n0 + 16 + m16] = fmaxf(acc1[r] + bias1, 0.f);
    }
    __syncthreads();

    int t = threadIdx.x;
    if (t < NF) {
        float accp = 0.f;
        int cur = -1;
        int lim = min(16, n - node_base);
        for (int i = 0; i < lim; ++i) {
            int g = gid[node_base + i];
            if (g != cur) {
                if (cur >= 0) atomicAdd(&sums[cur * NF + t], accp);
                accp = 0.f;
                cur = g;
            }
            accp += bf2f(f2bf(hblk[i][t]));    // keep bf16 rounding of h2 path
        }
        if (cur >= 0) atomicAdd(&sums[cur * NF + t], accp);
    }
}

__device__ __forceinline__ int lower_bound_i(const int* a, int n, int key) {
    int lo = 0, hi = n;
    while (lo < hi) {
        int mid = (lo + hi) >> 1;
        if (a[mid] < key) lo = mid + 1; else hi = mid;
    }
    return lo;
}

// ---------------------------------------------------------------------------
// Final projection: wave-parallel 128-dim dot, one wave per graph.
// ---------------------------------------------------------------------------
__global__ __launch_bounds__(64) void final_kernel(
    const float* __restrict__ sums, const int* __restrict__ gid, int n,
    const float* __restrict__ Wp, const float* __restrict__ bp,
    float* __restrict__ out) {
    __shared__ int range[2];
    int g = blockIdx.x;
    int lane = threadIdx.x;
    if (lane == 0) range[0] = lower_bound_i(gid, n, g);
    if (lane == 1) range[1] = lower_bound_i(gid, n, g + 1);
    __syncthreads();
    float cnt = fmaxf((float)(range[1] - range[0]), 1.0f);
    float inv = 1.0f / cnt;
    float s0 = sums[g * NF + lane] * inv;
    float s1 = sums[g * NF + 64 + lane] * inv;
#pragma unroll
    for (int c = 0; c < NCLS; ++c) {
        float p = s0 * Wp[lane * NCLS + c] + s1 * Wp[(64 + lane) * NCLS + c];
#pragma unroll
        for (int m = 1; m < 64; m <<= 1) p += __shfl_xor(p, m, 64);
        if (lane == 0) out[g * NCLS + c] = p + bp[c];
    }
}

extern "C" void kernel_launch(void* const* d_in, const int* in_sizes, int n_in,
                              void* d_out, int out_size, void* d_ws, size_t ws_size,
                              hipStream_t stream) {
    const float* feat = (const float*)d_in[0];
    const float* W1   = (const float*)d_in[1];
    const float* b1   = (const float*)d_in[2];
    const float* W2   = (const float*)d_in[3];
    const float* b2   = (const float*)d_in[4];
    const float* Wp   = (const float*)d_in[5];
    const float* bp   = (const float*)d_in[6];
    const int*   src  = (const int*)d_in[7];
    const int*   dst  = (const int*)d_in[8];
    const int*   gid  = (const int*)d_in[9];

    int ne = in_sizes[7];
    int n  = in_sizes[9];

    // Workspace (16B-aligned segments):
    unsigned short* featbf = (unsigned short*)d_ws;                  // n*128 u16
    unsigned short* h1     = featbf + (size_t)n * NF;                // n*128 u16
    unsigned int* records = (unsigned int*)(h1 + (size_t)n * NF);    // 256*PART_CAP u32
    int* eid      = (int*)(records + (size_t)NPARTS * PART_CAP);     // ne
    float* sums   = (float*)(eid + ne);                              // 64*128
    int* gcur     = (int*)(sums + NGRAPHS * NF);                     // 256
    unsigned short* Wt1 = (unsigned short*)(gcur + NPARTS);          // 128*128
    unsigned short* Wt2 = Wt1 + NF * NF;                             // 128*128
    int* offs     = (int*)(Wt2 + NF * NF);                           // n+1

    int nv4 = n * NF / 4;
    int splitblocks = (ne + SPLIT_TILE - 1) / SPLIT_TILE;
    int buildblocks = (n + PART_NODES - 1) >> PART_SHIFT;
    int ggblocks = (n + 15) / 16;

    hipMemsetAsync(gcur, 0, NPARTS * sizeof(int), stream);
    split_prep_kernel<<<splitblocks, 256, 0, stream>>>(
        src, dst, records, gcur, feat, featbf, W1, W2, Wt1, Wt2, sums, ne, nv4);
    build_kernel<<<buildblocks, 256, 0, stream>>>(records, gcur, offs, eid, n);

    gather_gemm1<<<ggblocks, 256, 0, stream>>>(featbf, offs, eid, Wt1, b1, h1, n);
    gather_gemm2_pool<<<ggblocks, 256, 0, stream>>>(h1, offs, eid, Wt2, b2, gid, sums, n);
    final_kernel<<<NGRAPHS, 64, 0, stream>>>(sums, gid, n, Wp, bp, (float*)d_out);
}